// Round 2
// baseline (1126.308 us; speedup 1.0000x reference)
//
#include <hip/hip_runtime.h>
#include <cstdint>

typedef _Float16 f16_t;
typedef __attribute__((ext_vector_type(8))) _Float16 f16x8;
typedef __attribute__((ext_vector_type(4))) float f32x4;

#define HP      160      // padded H (150 -> 160): h/c row stride, U K-dim
#define NCOL    640      // 4 groups (i,o,u,f) x 160
#define KXP     320      // padded X_SIZE (300 -> 320)
#define NNODES  524287
#define LEAF_S  262143
#define LEAF_M  262144
#define NVOCAB  50000

__device__ __forceinline__ float sigf(float x) { return 1.0f / (1.0f + __expf(-x)); }
__device__ __forceinline__ float tanhf_(float x) {
  float e = __expf(2.0f * x);
  return (e - 1.0f) / (e + 1.0f);
}
__device__ __forceinline__ f16x8 zero8() {
  f16x8 z;
#pragma unroll
  for (int i = 0; i < 8; ++i) z[i] = (_Float16)0.0f;
  return z;
}
__device__ __forceinline__ f32x4 zero4() {
  f32x4 z;
#pragma unroll
  for (int i = 0; i < 4; ++i) z[i] = 0.0f;
  return z;
}

// Transposed/padded fp16 weights: WreT[col][k] (640x320), UreT[col][k]
// (640x160), bre[col] fp32. col = g*160+j, g in {i,o,u,f}; zero padding.
__global__ void prep_params(const float* __restrict__ W_iou, const float* __restrict__ U_iou,
                            const float* __restrict__ b_iou, const float* __restrict__ W_f,
                            const float* __restrict__ U_f, const float* __restrict__ b_f,
                            f16_t* __restrict__ WreT, f16_t* __restrict__ UreT,
                            float* __restrict__ bre) {
  int idx = blockIdx.x * 256 + threadIdx.x;
  if (idx < NCOL * KXP) {
    int col = idx / KXP, k = idx % KXP;
    int g = col / HP, j = col % HP;
    float v = 0.0f;
    if (k < 300 && j < 150) v = (g < 3) ? W_iou[k * 450 + g * 150 + j] : W_f[k * 150 + j];
    WreT[idx] = (f16_t)v;
  } else if (idx < NCOL * KXP + NCOL * HP) {
    int i2 = idx - NCOL * KXP;
    int col = i2 / HP, k = i2 % HP;
    int g = col / HP, j = col % HP;
    float v = 0.0f;
    if (k < 150 && j < 150) v = (g < 3) ? U_iou[k * 450 + g * 150 + j] : U_f[k * 150 + j];
    UreT[i2] = (f16_t)v;
  } else if (idx < NCOL * KXP + NCOL * HP + NCOL) {
    int col = idx - (NCOL * KXP + NCOL * HP);
    int g = col / HP, j = col % HP;
    bre[col] = (j < 150) ? ((g < 3) ? b_iou[g * 150 + j] : b_f[j]) : 0.0f;
  }
}

// P[v][col] = (emb @ [W_iou|W_f] + bias)[v][col], fp16, 50000x640.
__global__ __launch_bounds__(256) void gemm_p(const float* __restrict__ emb,
                                              const f16_t* __restrict__ WreT,
                                              const float* __restrict__ bre,
                                              f16_t* __restrict__ P) {
  __shared__ __align__(16) f16_t A_sh[64 * 344];
  __shared__ __align__(16) f16_t B_sh[128 * 40];
  const int tid = threadIdx.x;
  const int wid = tid >> 6, lane = tid & 63, l15 = lane & 15, q = lane >> 4;
  const int row0 = blockIdx.x * 64;

#pragma unroll
  for (int i = 0; i < 10; ++i) {
    int ch = tid + 256 * i;
    int r = ch / 40, kc = (ch % 40) * 8;
    int grow = row0 + r;
#pragma unroll
    for (int e = 0; e < 8; ++e) {
      int k = kc + e;
      float v = (grow < NVOCAB && k < 300) ? emb[grow * 300 + k] : 0.0f;
      A_sh[r * 344 + k] = (f16_t)v;
    }
  }
  __syncthreads();

  for (int bn = 0; bn < 5; ++bn) {
    const int col0 = bn * 128;
    f32x4 acc[8];
#pragma unroll
    for (int t = 0; t < 8; ++t) acc[t] = zero4();
    for (int kk = 0; kk < KXP; kk += 32) {
#pragma unroll
      for (int i = 0; i < 2; ++i) {
        int ch = tid + 256 * i;
        int cidx = ch >> 2, kc = (ch & 3) * 8;
        *(f16x8*)&B_sh[cidx * 40 + kc] =
            *(const f16x8*)&WreT[(col0 + cidx) * KXP + kk + kc];
      }
      __syncthreads();
      f16x8 af = *(const f16x8*)&A_sh[(16 * wid + l15) * 344 + kk + q * 8];
#pragma unroll
      for (int t = 0; t < 8; ++t) {
        f16x8 bfr = *(const f16x8*)&B_sh[(t * 16 + l15) * 40 + q * 8];
        acc[t] = __builtin_amdgcn_mfma_f32_16x16x32_f16(af, bfr, acc[t], 0, 0, 0);
      }
      __syncthreads();
    }
#pragma unroll
    for (int t = 0; t < 8; ++t) {
      int col = col0 + t * 16 + l15;
      float bias = bre[col];
#pragma unroll
      for (int r2 = 0; r2 < 4; ++r2) {
        int row = row0 + 16 * wid + q * 4 + r2;
        if (row < NVOCAB) P[(long)row * NCOL + col] = (f16_t)(acc[t][r2] + bias);
      }
    }
  }
}

// Output rows for leaves: recompute h from P, project onto W_out.
__global__ __launch_bounds__(256) void leaf_out(const int* __restrict__ x_id,
                                                const f16_t* __restrict__ P,
                                                const float* __restrict__ W_out,
                                                const float* __restrict__ b_out,
                                                float* __restrict__ out) {
  __shared__ float Wo[752];
  const int tid = threadIdx.x;
  for (int i = tid; i < 750; i += 256) Wo[i] = W_out[i];
  __syncthreads();
  const int g = tid >> 4, l = tid & 15;
  const long node = (long)LEAF_S + blockIdx.x * 16 + g;
  const int xv = x_id[node];
  const f16_t* Pr = P + (long)xv * NCOL;
  float oacc[5] = {0, 0, 0, 0, 0};
  for (int j = l; j < 150; j += 16) {
    float iv = (float)Pr[j], ov = (float)Pr[HP + j], uv = (float)Pr[2 * HP + j];
    float cl = sigf(iv) * tanhf_(uv);
    float hl = sigf(ov) * tanhf_(cl);
#pragma unroll
    for (int m = 0; m < 5; ++m) oacc[m] += hl * Wo[j * 5 + m];
  }
#pragma unroll
  for (int m = 0; m < 5; ++m) {
    float v = oacc[m];
    v += __shfl_xor(v, 1);
    v += __shfl_xor(v, 2);
    v += __shfl_xor(v, 4);
    v += __shfl_xor(v, 8);
    if (l == 0) out[node * 5 + m] = v + b_out[m];
  }
}

// One level: 32 parents/block = 64 child rows. Z = h_children @ [U_iou|U_f]
// by MFMA; gate + out-projection fused in the epilogue (child pair = acc regs
// r, r+1 of one lane -> no cross-lane combine). LEAF: children are leaves;
// their h is recomputed from P during A-staging, their c stashed in LDS.
template <bool LEAF>
__global__ __launch_bounds__(256) void level_kernel(
    const int* __restrict__ x_id, const f16_t* __restrict__ P,
    const f16_t* __restrict__ UreT, const f16_t* __restrict__ h_child,
    const f16_t* __restrict__ c_child, f16_t* __restrict__ h_par,
    f16_t* __restrict__ c_par, const float* __restrict__ W_out,
    const float* __restrict__ b_out, float* __restrict__ out, int s, int M) {
  __shared__ __align__(16) f16_t A_sh[64 * 184];
  __shared__ __align__(16) f16_t B_sh[128 * 40];
  __shared__ f16_t C_sh[LEAF ? 64 * 160 : 16];
  __shared__ float Wo[800];
  const int tid = threadIdx.x;
  const int wid = tid >> 6, lane = tid & 63, l15 = lane & 15, q = lane >> 4;
  const int p0 = blockIdx.x * 32;
  int rowsValid = 2 * M - 2 * p0;
  if (rowsValid > 64) rowsValid = 64;

  for (int i = tid; i < 800; i += 256) Wo[i] = (i < 750) ? W_out[i] : 0.0f;

#pragma unroll
  for (int i = 0; i < 5; ++i) {
    int ch = tid + 256 * i;
    int r = ch / 20, kc = (ch % 20) * 8;
    if (LEAF) {
      const int xv = x_id[(long)LEAF_S + 2 * p0 + r];
      const f16_t* Pr = P + (long)xv * NCOL;
      f16x8 pi = *(const f16x8*)&Pr[kc];
      f16x8 po = *(const f16x8*)&Pr[HP + kc];
      f16x8 pu = *(const f16x8*)&Pr[2 * HP + kc];
      f16x8 hv;
#pragma unroll
      for (int e = 0; e < 8; ++e) {
        float cl = sigf((float)pi[e]) * tanhf_((float)pu[e]);
        float hl = sigf((float)po[e]) * tanhf_(cl);
        C_sh[r * 160 + kc + e] = (f16_t)cl;
        hv[e] = (_Float16)hl;
      }
      *(f16x8*)&A_sh[r * 184 + kc] = hv;
    } else {
      f16x8 v;
      if (r < rowsValid) v = *(const f16x8*)&h_child[(long)(2 * p0 + r) * HP + kc];
      else v = zero8();
      *(f16x8*)&A_sh[r * 184 + kc] = v;
    }
  }
  __syncthreads();

  float oacc[2][5];
#pragma unroll
  for (int rr = 0; rr < 2; ++rr)
#pragma unroll
    for (int m = 0; m < 5; ++m) oacc[rr][m] = 0.0f;

  for (int jt = 0; jt < 5; ++jt) {
    const int j0 = jt * 32;
    f32x4 acc[4][2];
#pragma unroll
    for (int g = 0; g < 4; ++g)
#pragma unroll
      for (int jh = 0; jh < 2; ++jh) acc[g][jh] = zero4();

    for (int kk = 0; kk < HP; kk += 32) {
#pragma unroll
      for (int i = 0; i < 2; ++i) {
        int ch = tid + 256 * i;
        int cidx = ch >> 2, kc = (ch & 3) * 8;
        int g = cidx >> 5, jj = cidx & 31;
        int col = g * HP + j0 + jj;
        *(f16x8*)&B_sh[cidx * 40 + kc] = *(const f16x8*)&UreT[col * HP + kk + kc];
      }
      __syncthreads();
      f16x8 af = *(const f16x8*)&A_sh[(16 * wid + l15) * 184 + kk + q * 8];
#pragma unroll
      for (int g = 0; g < 4; ++g)
#pragma unroll
        for (int jh = 0; jh < 2; ++jh) {
          f16x8 bfr = *(const f16x8*)&B_sh[(g * 32 + jh * 16 + l15) * 40 + q * 8];
          acc[g][jh] = __builtin_amdgcn_mfma_f32_16x16x32_f16(af, bfr, acc[g][jh], 0, 0, 0);
        }
      __syncthreads();
    }

#pragma unroll
    for (int rr = 0; rr < 2; ++rr) {
      const int r = rr * 2;
      const int lr0 = 16 * wid + q * 4 + r;  // even local child row
      const int pl = lr0 >> 1;               // local parent 0..31
      const bool valid = (p0 + pl) < M;
      const long pn = (long)s + p0 + (valid ? pl : 0);
      const int xv = x_id[pn];
      const f16_t* Pr = P + (long)xv * NCOL;
#pragma unroll
      for (int jh = 0; jh < 2; ++jh) {
        const int j = j0 + jh * 16 + l15;
        float ipre = (float)Pr[j]          + acc[0][jh][r] + acc[0][jh][r + 1];
        float opre = (float)Pr[HP + j]     + acc[1][jh][r] + acc[1][jh][r + 1];
        float upre = (float)Pr[2 * HP + j] + acc[2][jh][r] + acc[2][jh][r + 1];
        float pf   = (float)Pr[3 * HP + j];
        float fl = sigf(pf + acc[3][jh][r]);
        float fr = sigf(pf + acc[3][jh][r + 1]);
        float clv, crv;
        if (LEAF) {
          clv = (float)C_sh[lr0 * 160 + j];
          crv = (float)C_sh[(lr0 + 1) * 160 + j];
        } else {
          clv = valid ? (float)c_child[(long)(2 * p0 + lr0) * HP + j] : 0.0f;
          crv = valid ? (float)c_child[(long)(2 * p0 + lr0 + 1) * HP + j] : 0.0f;
        }
        float cn = sigf(ipre) * tanhf_(upre) + fl * clv + fr * crv;
        float hn = sigf(opre) * tanhf_(cn);
        if (valid) {
          h_par[(long)(p0 + pl) * HP + j] = (f16_t)hn;
          c_par[(long)(p0 + pl) * HP + j] = (f16_t)cn;
        }
#pragma unroll
        for (int m = 0; m < 5; ++m) oacc[rr][m] += hn * Wo[j * 5 + m];
      }
    }
  }

#pragma unroll
  for (int rr = 0; rr < 2; ++rr) {
    const int pl = 8 * wid + 2 * q + rr;
    const bool valid = (p0 + pl) < M;
#pragma unroll
    for (int m = 0; m < 5; ++m) {
      float v = oacc[rr][m];
      v += __shfl_xor(v, 1);
      v += __shfl_xor(v, 2);
      v += __shfl_xor(v, 4);
      v += __shfl_xor(v, 8);
      if (l15 == 0 && valid) out[((long)s + p0 + pl) * 5 + m] = v + b_out[m];
    }
  }
}

extern "C" void kernel_launch(void* const* d_in, const int* in_sizes, int n_in,
                              void* d_out, int out_size, void* d_ws, size_t ws_size,
                              hipStream_t stream) {
  const int* x_id   = (const int*)d_in[0];
  const float* emb  = (const float*)d_in[1];
  const float* W_iou = (const float*)d_in[2];
  const float* U_iou = (const float*)d_in[3];
  const float* b_iou = (const float*)d_in[4];
  const float* W_f   = (const float*)d_in[5];
  const float* U_f   = (const float*)d_in[6];
  const float* b_f   = (const float*)d_in[7];
  const float* W_out = (const float*)d_in[8];
  const float* b_out = (const float*)d_in[9];
  float* out = (float*)d_out;
  char* ws = (char*)d_ws;

  // workspace carve (bytes): total 190,446,080
  f16_t* WreT = (f16_t*)(ws + 0);              // 640*320*2     =    409,600
  f16_t* UreT = (f16_t*)(ws + 409600);         // 640*160*2     =    204,800
  float* bre  = (float*)(ws + 614400);         // 640*4         =      2,560
  f16_t* P    = (f16_t*)(ws + 616960);         // 50000*640*2   = 64,000,000
  f16_t* HA   = (f16_t*)(ws + 64616960);       // 131072*160*2  = 41,943,040  (odd levels)
  f16_t* HB   = (f16_t*)(ws + 106560000);      // 65536*160*2   = 20,971,520  (even levels)
  f16_t* CA   = (f16_t*)(ws + 127531520);      // 131072*160*2  = 41,943,040
  f16_t* CB   = (f16_t*)(ws + 169474560);      // 65536*160*2   = 20,971,520

  prep_params<<<1203, 256, 0, stream>>>(W_iou, U_iou, b_iou, W_f, U_f, b_f, WreT, UreT, bre);
  gemm_p<<<782, 256, 0, stream>>>(emb, WreT, bre, P);
  leaf_out<<<LEAF_M / 16, 256, 0, stream>>>(x_id, P, W_out, b_out, out);

  // level 17 (odd -> writes A buffers), children are leaves (from P)
  level_kernel<true><<<(131072 + 31) / 32, 256, 0, stream>>>(
      x_id, P, UreT, (const f16_t*)nullptr, (const f16_t*)nullptr, HA, CA,
      W_out, b_out, out, (1 << 17) - 1, 1 << 17);

  for (int lvl = 16; lvl >= 0; --lvl) {
    int s = (1 << lvl) - 1;
    int M = 1 << lvl;
    const f16_t* hc = ((lvl + 1) & 1) ? HA : HB;  // child level parity
    const f16_t* cc = ((lvl + 1) & 1) ? CA : CB;
    f16_t* hp = (lvl & 1) ? HA : HB;
    f16_t* cp = (lvl & 1) ? CA : CB;
    level_kernel<false><<<(M + 31) / 32, 256, 0, stream>>>(
        x_id, P, UreT, hc, cc, hp, cp, W_out, b_out, out, s, M);
  }

  (void)in_sizes; (void)n_in; (void)out_size; (void)ws_size;
}

// Round 3
// 1123.491 us; speedup vs baseline: 1.0025x; 1.0025x over previous
//
#include <hip/hip_runtime.h>
#include <cstdint>

typedef _Float16 f16_t;
typedef __attribute__((ext_vector_type(8))) _Float16 f16x8;
typedef __attribute__((ext_vector_type(4))) _Float16 f16x4;
typedef __attribute__((ext_vector_type(4))) float f32x4;

#define HP      160      // padded H (150 -> 160): h/c row stride, U K-dim
#define NCOL    640      // 160 j x 4 gates (P is [v][j][g] interleaved)
#define KXP     320      // padded X_SIZE (300 -> 320)
#define NNODES  524287
#define LEAF_S  262143
#define LEAF_M  262144
#define NVOCAB  50000

__device__ __forceinline__ float frcp(float x) { return __builtin_amdgcn_rcpf(x); }
__device__ __forceinline__ float sigf(float x) { return frcp(1.0f + __expf(-x)); }
__device__ __forceinline__ float tanhf_(float x) {
  return 1.0f - 2.0f * frcp(1.0f + __expf(2.0f * x));
}
__device__ __forceinline__ f16x8 zero8() {
  f16x8 z;
#pragma unroll
  for (int i = 0; i < 8; ++i) z[i] = (_Float16)0.0f;
  return z;
}
__device__ __forceinline__ f32x4 zero4() {
  f32x4 z;
#pragma unroll
  for (int i = 0; i < 4; ++i) z[i] = 0.0f;
  return z;
}

// WreT[colIdx][k] with colIdx = j*4+g (matches P's interleaved layout);
// UreT[col][k] with col = g*160+j (g-major, matches B staging);
// bre[colIdx] fp32 interleaved.
__global__ void prep_params(const float* __restrict__ W_iou, const float* __restrict__ U_iou,
                            const float* __restrict__ b_iou, const float* __restrict__ W_f,
                            const float* __restrict__ U_f, const float* __restrict__ b_f,
                            f16_t* __restrict__ WreT, f16_t* __restrict__ UreT,
                            float* __restrict__ bre) {
  int idx = blockIdx.x * 256 + threadIdx.x;
  if (idx < NCOL * KXP) {
    int col = idx / KXP, k = idx % KXP;
    int j = col >> 2, g = col & 3;
    float v = 0.0f;
    if (k < 300 && j < 150) v = (g < 3) ? W_iou[k * 450 + g * 150 + j] : W_f[k * 150 + j];
    WreT[idx] = (f16_t)v;
  } else if (idx < NCOL * KXP + NCOL * HP) {
    int i2 = idx - NCOL * KXP;
    int col = i2 / HP, k = i2 % HP;
    int g = col / HP, j = col % HP;
    g = col / HP; j = col % HP;   // col = g*160+j
    g = col / 160; j = col % 160;
    float v = 0.0f;
    if (k < 150 && j < 150) v = (g < 3) ? U_iou[k * 450 + g * 150 + j] : U_f[k * 150 + j];
    UreT[i2] = (f16_t)v;
  } else if (idx < NCOL * KXP + NCOL * HP + NCOL) {
    int col = idx - (NCOL * KXP + NCOL * HP);
    int j = col >> 2, g = col & 3;
    bre[col] = (j < 150) ? ((g < 3) ? b_iou[g * 150 + j] : b_f[j]) : 0.0f;
  }
}

// P[v][j][g] = (emb @ W + b), fp16, 50000 x 640 (columns already interleaved
// because WreT/bre are stored in interleaved column order).
__global__ __launch_bounds__(256) void gemm_p(const float* __restrict__ emb,
                                              const f16_t* __restrict__ WreT,
                                              const float* __restrict__ bre,
                                              f16_t* __restrict__ P) {
  __shared__ __align__(16) f16_t A_sh[64 * 328];
  __shared__ __align__(16) f16_t B_sh[128 * 40];
  const int tid = threadIdx.x;
  const int wid = tid >> 6, lane = tid & 63, l15 = lane & 15, q = lane >> 4;
  const int row0 = blockIdx.x * 64;

#pragma unroll
  for (int i = 0; i < 10; ++i) {
    int ch = tid + 256 * i;
    int r = ch / 40, kc = (ch % 40) * 8;
    int grow = row0 + r;
    f16x8 hv;
    if (grow < NVOCAB && kc + 8 <= 300) {
      float4 a = *(const float4*)&emb[grow * 300 + kc];
      float4 b = *(const float4*)&emb[grow * 300 + kc + 4];
      hv[0] = (_Float16)a.x; hv[1] = (_Float16)a.y; hv[2] = (_Float16)a.z; hv[3] = (_Float16)a.w;
      hv[4] = (_Float16)b.x; hv[5] = (_Float16)b.y; hv[6] = (_Float16)b.z; hv[7] = (_Float16)b.w;
    } else {
#pragma unroll
      for (int e = 0; e < 8; ++e) {
        int k = kc + e;
        float v = (grow < NVOCAB && k < 300) ? emb[grow * 300 + k] : 0.0f;
        hv[e] = (_Float16)v;
      }
    }
    *(f16x8*)&A_sh[r * 328 + kc] = hv;
  }
  __syncthreads();

  for (int bn = 0; bn < 5; ++bn) {
    const int col0 = bn * 128;
    f32x4 acc[8];
#pragma unroll
    for (int t = 0; t < 8; ++t) acc[t] = zero4();
    for (int kk = 0; kk < KXP; kk += 32) {
#pragma unroll
      for (int i = 0; i < 2; ++i) {
        int ch = tid + 256 * i;
        int cidx = ch >> 2, kc = (ch & 3) * 8;
        *(f16x8*)&B_sh[cidx * 40 + kc] =
            *(const f16x8*)&WreT[(col0 + cidx) * KXP + kk + kc];
      }
      __syncthreads();
      f16x8 af = *(const f16x8*)&A_sh[(16 * wid + l15) * 328 + kk + q * 8];
#pragma unroll
      for (int t = 0; t < 8; ++t) {
        f16x8 bfr = *(const f16x8*)&B_sh[(t * 16 + l15) * 40 + q * 8];
        acc[t] = __builtin_amdgcn_mfma_f32_16x16x32_f16(af, bfr, acc[t], 0, 0, 0);
      }
      __syncthreads();
    }
#pragma unroll
    for (int t = 0; t < 8; ++t) {
      int col = col0 + t * 16 + l15;
      float bias = bre[col];
#pragma unroll
      for (int r2 = 0; r2 < 4; ++r2) {
        int row = row0 + 16 * wid + q * 4 + r2;
        if (row < NVOCAB) P[(long)row * NCOL + col] = (f16_t)(acc[t][r2] + bias);
      }
    }
  }
}

// ---------------- shared non-leaf level tile ----------------
// 32 parents (p0..p0+31) = 64 child rows. A = child h staged in LDS; MFMA
// against UreT; epilogue reads parent P row (one 8B gather/elem), child c
// from c_child, fuses gates + out-projection.
__device__ __forceinline__ void level_tile(
    const int* __restrict__ x_id, const f16_t* __restrict__ P,
    const f16_t* __restrict__ UreT, const f16_t* __restrict__ h_child,
    const f16_t* __restrict__ c_child, f16_t* __restrict__ h_par,
    f16_t* __restrict__ c_par, const float* Wo, const float* __restrict__ b_out,
    float* __restrict__ out, int s, int M, int p0, f16_t* A_sh, f16_t* B_sh) {
  const int tid = threadIdx.x;
  const int wid = tid >> 6, lane = tid & 63, l15 = lane & 15, q = lane >> 4;
  int rowsValid = 2 * M - 2 * p0;
  if (rowsValid > 64) rowsValid = 64;

#pragma unroll
  for (int i = 0; i < 5; ++i) {
    int ch = tid + 256 * i;
    int r = ch / 20, kc = (ch % 20) * 8;
    f16x8 v;
    if (r < rowsValid) v = *(const f16x8*)&h_child[(long)(2 * p0 + r) * HP + kc];
    else v = zero8();
    *(f16x8*)&A_sh[r * 184 + kc] = v;
  }
  __syncthreads();

  int xvp[2]; long pnode[2]; int plg[2]; bool valid[2]; int lr0v[2];
#pragma unroll
  for (int rr = 0; rr < 2; ++rr) {
    int lr0 = 16 * wid + q * 4 + rr * 2;
    int pl = lr0 >> 1;
    valid[rr] = (p0 + pl) < M;
    long pn = (long)s + p0 + (valid[rr] ? pl : 0);
    pnode[rr] = pn; plg[rr] = p0 + pl; lr0v[rr] = lr0;
    xvp[rr] = x_id[pn];
  }

  float oacc[2][5];
#pragma unroll
  for (int rr = 0; rr < 2; ++rr)
#pragma unroll
    for (int m = 0; m < 5; ++m) oacc[rr][m] = 0.0f;

  for (int jt = 0; jt < 5; ++jt) {
    const int j0 = jt * 32;
    f32x4 acc[4][2];
#pragma unroll
    for (int g = 0; g < 4; ++g)
#pragma unroll
      for (int jh = 0; jh < 2; ++jh) acc[g][jh] = zero4();

    for (int kk = 0; kk < HP; kk += 32) {
#pragma unroll
      for (int i = 0; i < 2; ++i) {
        int ch = tid + 256 * i;
        int cidx = ch >> 2, kc = (ch & 3) * 8;
        int g = cidx >> 5, jj = cidx & 31;
        int col = g * HP + j0 + jj;
        *(f16x8*)&B_sh[cidx * 40 + kc] = *(const f16x8*)&UreT[col * HP + kk + kc];
      }
      __syncthreads();
      f16x8 af = *(const f16x8*)&A_sh[(16 * wid + l15) * 184 + kk + q * 8];
#pragma unroll
      for (int g = 0; g < 4; ++g)
#pragma unroll
        for (int jh = 0; jh < 2; ++jh) {
          f16x8 bfr = *(const f16x8*)&B_sh[(g * 32 + jh * 16 + l15) * 40 + q * 8];
          acc[g][jh] = __builtin_amdgcn_mfma_f32_16x16x32_f16(af, bfr, acc[g][jh], 0, 0, 0);
        }
      __syncthreads();
    }

#pragma unroll
    for (int rr = 0; rr < 2; ++rr) {
      const int r = rr * 2;
      const f16_t* Prp = P + (long)xvp[rr] * NCOL;
#pragma unroll
      for (int jh = 0; jh < 2; ++jh) {
        const int j = j0 + jh * 16 + l15;
        f16x4 pp = *(const f16x4*)&Prp[j * 4];
        float ipre = (float)pp[0] + acc[0][jh][r] + acc[0][jh][r + 1];
        float opre = (float)pp[1] + acc[1][jh][r] + acc[1][jh][r + 1];
        float upre = (float)pp[2] + acc[2][jh][r] + acc[2][jh][r + 1];
        float pf   = (float)pp[3];
        float fl = sigf(pf + acc[3][jh][r]);
        float fr = sigf(pf + acc[3][jh][r + 1]);
        float clv = valid[rr] ? (float)c_child[(long)(2 * p0 + lr0v[rr]) * HP + j] : 0.0f;
        float crv = valid[rr] ? (float)c_child[(long)(2 * p0 + lr0v[rr] + 1) * HP + j] : 0.0f;
        float cn = sigf(ipre) * tanhf_(upre) + fl * clv + fr * crv;
        float hn = sigf(opre) * tanhf_(cn);
        if (valid[rr]) {
          h_par[(long)plg[rr] * HP + j] = (f16_t)hn;
          c_par[(long)plg[rr] * HP + j] = (f16_t)cn;
        }
#pragma unroll
        for (int m = 0; m < 5; ++m) oacc[rr][m] += hn * Wo[j * 5 + m];
      }
    }
  }

#pragma unroll
  for (int rr = 0; rr < 2; ++rr) {
#pragma unroll
    for (int m = 0; m < 5; ++m) {
      float v = oacc[rr][m];
      v += __shfl_xor(v, 1);
      v += __shfl_xor(v, 2);
      v += __shfl_xor(v, 4);
      v += __shfl_xor(v, 8);
      if (l15 == 0 && valid[rr]) out[pnode[rr] * 5 + m] = v + b_out[m];
    }
  }
}

__global__ __launch_bounds__(256, 4) void level_mid_kernel(
    const int* __restrict__ x_id, const f16_t* __restrict__ P,
    const f16_t* __restrict__ UreT, const f16_t* __restrict__ h_child,
    const f16_t* __restrict__ c_child, f16_t* __restrict__ h_par,
    f16_t* __restrict__ c_par, const float* __restrict__ W_out,
    const float* __restrict__ b_out, float* __restrict__ out, int s, int M) {
  __shared__ __align__(16) f16_t A_sh[64 * 184];
  __shared__ __align__(16) f16_t B_sh[128 * 40];
  __shared__ float Wo[800];
  for (int i = threadIdx.x; i < 800; i += 256) Wo[i] = (i < 750) ? W_out[i] : 0.0f;
  level_tile(x_id, P, UreT, h_child, c_child, h_par, c_par, Wo, b_out, out,
             s, M, blockIdx.x * 32, A_sh, B_sh);
}

// Levels 5..0 (M<=32): one block, barriers between levels.
__global__ __launch_bounds__(256, 4) void tail_kernel(
    const int* __restrict__ x_id, const f16_t* __restrict__ P,
    const f16_t* __restrict__ UreT, f16_t* __restrict__ HA, f16_t* __restrict__ HB,
    f16_t* __restrict__ CA, f16_t* __restrict__ CB, const float* __restrict__ W_out,
    const float* __restrict__ b_out, float* __restrict__ out) {
  __shared__ __align__(16) f16_t A_sh[64 * 184];
  __shared__ __align__(16) f16_t B_sh[128 * 40];
  __shared__ float Wo[800];
  for (int i = threadIdx.x; i < 800; i += 256) Wo[i] = (i < 750) ? W_out[i] : 0.0f;
  for (int lvl = 5; lvl >= 0; --lvl) {
    int s = (1 << lvl) - 1, M = 1 << lvl;
    const f16_t* hc = ((lvl + 1) & 1) ? HA : HB;
    const f16_t* cc = ((lvl + 1) & 1) ? CA : CB;
    f16_t* hp = (lvl & 1) ? HA : HB;
    f16_t* cp = (lvl & 1) ? CA : CB;
    level_tile(x_id, P, UreT, hc, cc, hp, cp, Wo, b_out, out, s, M, 0, A_sh, B_sh);
    __syncthreads();
  }
}

// Level 17: children are leaves. Leaf h recomputed from P during A staging;
// leaf c recomputed in the epilogue (one 8B gather + ~10 VALU per elem);
// leaf out-projection fused at the end from A_sh (replaces leaf_out kernel).
__global__ __launch_bounds__(256, 4) void level17_kernel(
    const int* __restrict__ x_id, const f16_t* __restrict__ P,
    const f16_t* __restrict__ UreT, f16_t* __restrict__ h_par,
    f16_t* __restrict__ c_par, const float* __restrict__ W_out,
    const float* __restrict__ b_out, float* __restrict__ out) {
  __shared__ __align__(16) f16_t A_sh[64 * 184];
  __shared__ __align__(16) f16_t B_sh[128 * 40];
  __shared__ float Wo[800];
  const int tid = threadIdx.x;
  const int wid = tid >> 6, lane = tid & 63, l15 = lane & 15, q = lane >> 4;
  const int p0 = blockIdx.x * 32;
  const int s = (1 << 17) - 1;

  for (int i = tid; i < 800; i += 256) Wo[i] = (i < 750) ? W_out[i] : 0.0f;

#pragma unroll
  for (int i = 0; i < 5; ++i) {
    int ch = tid + 256 * i;
    int r = ch / 20, kc = (ch % 20) * 8;
    const int xv = x_id[LEAF_S + 2 * p0 + r];
    const f16_t* Pr = P + (long)xv * NCOL + kc * 4;
    f16x8 pk0 = *(const f16x8*)&Pr[0];
    f16x8 pk1 = *(const f16x8*)&Pr[8];
    f16x8 pk2 = *(const f16x8*)&Pr[16];
    f16x8 pk3 = *(const f16x8*)&Pr[24];
    f16x8 hv;
#pragma unroll
    for (int e = 0; e < 8; ++e) {
      f16x8 blk = (e < 2) ? pk0 : (e < 4) ? pk1 : (e < 6) ? pk2 : pk3;
      int hf = (e & 1) * 4;
      float iv = (float)blk[hf + 0], ov = (float)blk[hf + 1], uv = (float)blk[hf + 2];
      float cl = sigf(iv) * tanhf_(uv);
      float hl = sigf(ov) * tanhf_(cl);
      hv[e] = (_Float16)hl;
    }
    *(f16x8*)&A_sh[r * 184 + kc] = hv;
  }
  __syncthreads();

  int xvp[2], xvl[2], xvr[2]; long pnode[2]; int plg[2];
#pragma unroll
  for (int rr = 0; rr < 2; ++rr) {
    int lr0 = 16 * wid + q * 4 + rr * 2;
    int pl = lr0 >> 1;
    long pn = (long)s + p0 + pl;
    pnode[rr] = pn; plg[rr] = p0 + pl;
    xvp[rr] = x_id[pn];
    xvl[rr] = x_id[2 * pn + 1];
    xvr[rr] = x_id[2 * pn + 2];
  }

  float oacc[2][5];
#pragma unroll
  for (int rr = 0; rr < 2; ++rr)
#pragma unroll
    for (int m = 0; m < 5; ++m) oacc[rr][m] = 0.0f;

  for (int jt = 0; jt < 5; ++jt) {
    const int j0 = jt * 32;
    f32x4 acc[4][2];
#pragma unroll
    for (int g = 0; g < 4; ++g)
#pragma unroll
      for (int jh = 0; jh < 2; ++jh) acc[g][jh] = zero4();

    for (int kk = 0; kk < HP; kk += 32) {
#pragma unroll
      for (int i = 0; i < 2; ++i) {
        int ch = tid + 256 * i;
        int cidx = ch >> 2, kc = (ch & 3) * 8;
        int g = cidx >> 5, jj = cidx & 31;
        int col = g * HP + j0 + jj;
        *(f16x8*)&B_sh[cidx * 40 + kc] = *(const f16x8*)&UreT[col * HP + kk + kc];
      }
      __syncthreads();
      f16x8 af = *(const f16x8*)&A_sh[(16 * wid + l15) * 184 + kk + q * 8];
#pragma unroll
      for (int g = 0; g < 4; ++g)
#pragma unroll
        for (int jh = 0; jh < 2; ++jh) {
          f16x8 bfr = *(const f16x8*)&B_sh[(g * 32 + jh * 16 + l15) * 40 + q * 8];
          acc[g][jh] = __builtin_amdgcn_mfma_f32_16x16x32_f16(af, bfr, acc[g][jh], 0, 0, 0);
        }
      __syncthreads();
    }

#pragma unroll
    for (int rr = 0; rr < 2; ++rr) {
      const int r = rr * 2;
      const f16_t* Prp = P + (long)xvp[rr] * NCOL;
      const f16_t* Prl = P + (long)xvl[rr] * NCOL;
      const f16_t* Prr_ = P + (long)xvr[rr] * NCOL;
#pragma unroll
      for (int jh = 0; jh < 2; ++jh) {
        const int j = j0 + jh * 16 + l15;
        f16x4 pp = *(const f16x4*)&Prp[j * 4];
        f16x4 pcl = *(const f16x4*)&Prl[j * 4];
        f16x4 pcr = *(const f16x4*)&Prr_[j * 4];
        float ipre = (float)pp[0] + acc[0][jh][r] + acc[0][jh][r + 1];
        float opre = (float)pp[1] + acc[1][jh][r] + acc[1][jh][r + 1];
        float upre = (float)pp[2] + acc[2][jh][r] + acc[2][jh][r + 1];
        float pf   = (float)pp[3];
        float fl = sigf(pf + acc[3][jh][r]);
        float fr = sigf(pf + acc[3][jh][r + 1]);
        float clv = sigf((float)pcl[0]) * tanhf_((float)pcl[2]);
        float crv = sigf((float)pcr[0]) * tanhf_((float)pcr[2]);
        float cn = sigf(ipre) * tanhf_(upre) + fl * clv + fr * crv;
        float hn = sigf(opre) * tanhf_(cn);
        h_par[(long)plg[rr] * HP + j] = (f16_t)hn;
        c_par[(long)plg[rr] * HP + j] = (f16_t)cn;
#pragma unroll
        for (int m = 0; m < 5; ++m) oacc[rr][m] += hn * Wo[j * 5 + m];
      }
    }
  }

#pragma unroll
  for (int rr = 0; rr < 2; ++rr) {
#pragma unroll
    for (int m = 0; m < 5; ++m) {
      float v = oacc[rr][m];
      v += __shfl_xor(v, 1);
      v += __shfl_xor(v, 2);
      v += __shfl_xor(v, 4);
      v += __shfl_xor(v, 8);
      if (l15 == 0) out[pnode[rr] * 5 + m] = v + b_out[m];
    }
  }

  // fused out-projection for the 64 leaf children (h is in A_sh)
  {
    const int row = 16 * wid + l15;
    const int jb = q * 40;
    float po[5] = {0, 0, 0, 0, 0};
    for (int t = 0; t < 40; ++t) {
      int j = jb + t;
      float hv = (float)A_sh[row * 184 + j];
#pragma unroll
      for (int m = 0; m < 5; ++m) po[m] += hv * Wo[j * 5 + m];
    }
#pragma unroll
    for (int m = 0; m < 5; ++m) {
      float v = po[m];
      v += __shfl_xor(v, 16);
      v += __shfl_xor(v, 32);
      if (q == 0) out[((long)LEAF_S + 2 * p0 + row) * 5 + m] = v + b_out[m];
    }
  }
}

extern "C" void kernel_launch(void* const* d_in, const int* in_sizes, int n_in,
                              void* d_out, int out_size, void* d_ws, size_t ws_size,
                              hipStream_t stream) {
  const int* x_id   = (const int*)d_in[0];
  const float* emb  = (const float*)d_in[1];
  const float* W_iou = (const float*)d_in[2];
  const float* U_iou = (const float*)d_in[3];
  const float* b_iou = (const float*)d_in[4];
  const float* W_f   = (const float*)d_in[5];
  const float* U_f   = (const float*)d_in[6];
  const float* b_f   = (const float*)d_in[7];
  const float* W_out = (const float*)d_in[8];
  const float* b_out = (const float*)d_in[9];
  float* out = (float*)d_out;
  char* ws = (char*)d_ws;

  // workspace carve (bytes): total 190,446,080
  f16_t* WreT = (f16_t*)(ws + 0);              // 640*320*2     =    409,600
  f16_t* UreT = (f16_t*)(ws + 409600);         // 640*160*2     =    204,800
  float* bre  = (float*)(ws + 614400);         // 640*4         =      2,560
  f16_t* P    = (f16_t*)(ws + 616960);         // 50000*640*2   = 64,000,000
  f16_t* HA   = (f16_t*)(ws + 64616960);       // 131072*160*2  = 41,943,040  (odd levels)
  f16_t* HB   = (f16_t*)(ws + 106560000);      // 65536*160*2   = 20,971,520  (even levels)
  f16_t* CA   = (f16_t*)(ws + 127531520);      // 131072*160*2  = 41,943,040
  f16_t* CB   = (f16_t*)(ws + 169474560);      // 65536*160*2   = 20,971,520

  prep_params<<<1203, 256, 0, stream>>>(W_iou, U_iou, b_iou, W_f, U_f, b_f, WreT, UreT, bre);
  gemm_p<<<782, 256, 0, stream>>>(emb, WreT, bre, P);

  level17_kernel<<<4096, 256, 0, stream>>>(x_id, P, UreT, HA, CA, W_out, b_out, out);

  for (int lvl = 16; lvl >= 6; --lvl) {
    int s = (1 << lvl) - 1;
    int M = 1 << lvl;
    const f16_t* hc = ((lvl + 1) & 1) ? HA : HB;
    const f16_t* cc = ((lvl + 1) & 1) ? CA : CB;
    f16_t* hp = (lvl & 1) ? HA : HB;
    f16_t* cp = (lvl & 1) ? CA : CB;
    level_mid_kernel<<<M / 32, 256, 0, stream>>>(x_id, P, UreT, hc, cc, hp, cp,
                                                 W_out, b_out, out, s, M);
  }
  tail_kernel<<<1, 256, 0, stream>>>(x_id, P, UreT, HA, HB, CA, CB, W_out, b_out, out);

  (void)in_sizes; (void)n_in; (void)out_size; (void)ws_size;
}

// Round 4
// 866.476 us; speedup vs baseline: 1.2999x; 1.2966x over previous
//
#include <hip/hip_runtime.h>
#include <cstdint>

typedef _Float16 f16_t;
typedef __attribute__((ext_vector_type(8))) _Float16 f16x8;
typedef __attribute__((ext_vector_type(4))) _Float16 f16x4;
typedef __attribute__((ext_vector_type(4))) float f32x4;

#define HP      160      // padded H (150 -> 160): h/c row stride, U K-dim
#define NCOL    640      // 160 j x 4 gates (P is [v][j][g] interleaved)
#define KXP     320      // padded X_SIZE (300 -> 320)
#define NNODES  524287
#define LEAF_S  262143
#define LEAF_M  262144
#define NVOCAB  50000
#define AST     168      // A_sh stride (f16): 16B-aligned, 2-way-bank-free

__device__ __forceinline__ float frcp(float x) { return __builtin_amdgcn_rcpf(x); }
__device__ __forceinline__ float sigf(float x) { return frcp(1.0f + __expf(-x)); }
__device__ __forceinline__ float tanhf_(float x) {
  return 1.0f - 2.0f * frcp(1.0f + __expf(2.0f * x));
}
__device__ __forceinline__ f16x8 zero8() {
  f16x8 z;
#pragma unroll
  for (int i = 0; i < 8; ++i) z[i] = (_Float16)0.0f;
  return z;
}
__device__ __forceinline__ f32x4 zero4() {
  f32x4 z;
#pragma unroll
  for (int i = 0; i < 4; ++i) z[i] = 0.0f;
  return z;
}

// WreT[colIdx][k], colIdx = j*4+g (interleaved, matches P);
// UreT[col][k], col = g*160+j (g-major, matches B staging); bre interleaved.
__global__ void prep_params(const float* __restrict__ W_iou, const float* __restrict__ U_iou,
                            const float* __restrict__ b_iou, const float* __restrict__ W_f,
                            const float* __restrict__ U_f, const float* __restrict__ b_f,
                            f16_t* __restrict__ WreT, f16_t* __restrict__ UreT,
                            float* __restrict__ bre) {
  int idx = blockIdx.x * 256 + threadIdx.x;
  if (idx < NCOL * KXP) {
    int col = idx / KXP, k = idx % KXP;
    int j = col >> 2, g = col & 3;
    float v = 0.0f;
    if (k < 300 && j < 150) v = (g < 3) ? W_iou[k * 450 + g * 150 + j] : W_f[k * 150 + j];
    WreT[idx] = (f16_t)v;
  } else if (idx < NCOL * KXP + NCOL * HP) {
    int i2 = idx - NCOL * KXP;
    int col = i2 / HP, k = i2 % HP;
    int g = col / 160, j = col % 160;
    float v = 0.0f;
    if (k < 150 && j < 150) v = (g < 3) ? U_iou[k * 450 + g * 150 + j] : U_f[k * 150 + j];
    UreT[i2] = (f16_t)v;
  } else if (idx < NCOL * KXP + NCOL * HP + NCOL) {
    int col = idx - (NCOL * KXP + NCOL * HP);
    int j = col >> 2, g = col & 3;
    bre[col] = (j < 150) ? ((g < 3) ? b_iou[g * 150 + j] : b_f[j]) : 0.0f;
  }
}

// P[v][j][g] = emb @ W + b, fp16, 50000 x 640 (interleaved cols).
__global__ __launch_bounds__(256) void gemm_p(const float* __restrict__ emb,
                                              const f16_t* __restrict__ WreT,
                                              const float* __restrict__ bre,
                                              f16_t* __restrict__ P) {
  __shared__ __align__(16) f16_t A_sh[64 * 328];
  __shared__ __align__(16) f16_t B_sh[128 * 40];
  const int tid = threadIdx.x;
  const int wid = tid >> 6, lane = tid & 63, l15 = lane & 15, q = lane >> 4;
  const int row0 = blockIdx.x * 64;

#pragma unroll
  for (int i = 0; i < 10; ++i) {
    int ch = tid + 256 * i;
    int r = ch / 40, kc = (ch % 40) * 8;
    int grow = row0 + r;
    f16x8 hv;
    if (grow < NVOCAB && kc + 8 <= 300) {
      float4 a = *(const float4*)&emb[grow * 300 + kc];
      float4 b = *(const float4*)&emb[grow * 300 + kc + 4];
      hv[0] = (_Float16)a.x; hv[1] = (_Float16)a.y; hv[2] = (_Float16)a.z; hv[3] = (_Float16)a.w;
      hv[4] = (_Float16)b.x; hv[5] = (_Float16)b.y; hv[6] = (_Float16)b.z; hv[7] = (_Float16)b.w;
    } else {
#pragma unroll
      for (int e = 0; e < 8; ++e) {
        int k = kc + e;
        float v = (grow < NVOCAB && k < 300) ? emb[grow * 300 + k] : 0.0f;
        hv[e] = (_Float16)v;
      }
    }
    *(f16x8*)&A_sh[r * 328 + kc] = hv;
  }
  __syncthreads();

  for (int bn = 0; bn < 5; ++bn) {
    const int col0 = bn * 128;
    f32x4 acc[8];
#pragma unroll
    for (int t = 0; t < 8; ++t) acc[t] = zero4();
    for (int kk = 0; kk < KXP; kk += 32) {
#pragma unroll
      for (int i = 0; i < 2; ++i) {
        int ch = tid + 256 * i;
        int cidx = ch >> 2, kc = (ch & 3) * 8;
        *(f16x8*)&B_sh[cidx * 40 + kc] =
            *(const f16x8*)&WreT[(col0 + cidx) * KXP + kk + kc];
      }
      __syncthreads();
      f16x8 af = *(const f16x8*)&A_sh[(16 * wid + l15) * 328 + kk + q * 8];
#pragma unroll
      for (int t = 0; t < 8; ++t) {
        f16x8 bfr = *(const f16x8*)&B_sh[(t * 16 + l15) * 40 + q * 8];
        acc[t] = __builtin_amdgcn_mfma_f32_16x16x32_f16(af, bfr, acc[t], 0, 0, 0);
      }
      __syncthreads();
    }
#pragma unroll
    for (int t = 0; t < 8; ++t) {
      int col = col0 + t * 16 + l15;
      float bias = bre[col];
#pragma unroll
      for (int r2 = 0; r2 < 4; ++r2) {
        int row = row0 + 16 * wid + q * 4 + r2;
        if (row < NVOCAB) P[(long)row * NCOL + col] = (f16_t)(acc[t][r2] + bias);
      }
    }
  }
}

// Vocab-space leaf h/c tables: Hleaf[v][j], Cleaf[v][j] (f16).
__global__ void leafhc_kernel(const f16_t* __restrict__ P, f16_t* __restrict__ Hleaf,
                              f16_t* __restrict__ Cleaf) {
  int idx = blockIdx.x * 256 + threadIdx.x;
  if (idx >= NVOCAB * 80) return;
  int v = idx / 80, t = idx % 80;
  f16x8 pk = *(const f16x8*)&P[(long)v * NCOL + t * 8];
#pragma unroll
  for (int e = 0; e < 2; ++e) {
    float iv = (float)pk[e * 4 + 0], ov = (float)pk[e * 4 + 1], uv = (float)pk[e * 4 + 2];
    float cl = sigf(iv) * tanhf_(uv);
    float hl = sigf(ov) * tanhf_(cl);
    Hleaf[(long)v * HP + t * 2 + e] = (f16_t)hl;   // pads (t>=75) stay exactly 0
    Cleaf[(long)v * HP + t * 2 + e] = (f16_t)cl;
  }
}

// Oleaf[v] = Hleaf[v] @ W_out + b_out (row stride 8 floats for alignment).
__global__ void oleaf_kernel(const f16_t* __restrict__ Hleaf, const float* __restrict__ W_out,
                             const float* __restrict__ b_out, float* __restrict__ Oleaf) {
  const int tid = threadIdx.x;
  const int row = blockIdx.x * 16 + (tid >> 4), l = tid & 15;
  if (row >= NVOCAB) return;
  float acc[5] = {0, 0, 0, 0, 0};
  for (int j = l; j < 150; j += 16) {
    float hv = (float)Hleaf[(long)row * HP + j];
#pragma unroll
    for (int m = 0; m < 5; ++m) acc[m] += hv * W_out[j * 5 + m];
  }
#pragma unroll
  for (int m = 0; m < 5; ++m) {
    float vv = acc[m];
    vv += __shfl_xor(vv, 1);
    vv += __shfl_xor(vv, 2);
    vv += __shfl_xor(vv, 4);
    vv += __shfl_xor(vv, 8);
    if (l == 0) Oleaf[(long)row * 8 + m] = vv + b_out[m];
  }
}

// Leaf output rows: pure 20B gather from Oleaf.
__global__ void leafout_kernel(const int* __restrict__ x_id, const float* __restrict__ Oleaf,
                               float* __restrict__ out) {
  int leaf = blockIdx.x * 256 + threadIdx.x;
  int xv = x_id[LEAF_S + leaf];
  const float* O = Oleaf + (long)xv * 8;
  float4 o4 = *(const float4*)O;
  float o5 = O[4];
  long base = ((long)LEAF_S + leaf) * 5;
  out[base + 0] = o4.x; out[base + 1] = o4.y; out[base + 2] = o4.z;
  out[base + 3] = o4.w; out[base + 4] = o5;
}

// Two fused levels per block: 64 children -> 32 parents (level s1) -> 16
// grandparents (level (s1-1)/2). Pass-1 parent h -> A2_sh (LDS), c -> C_sh;
// pass-2 GEMMs A2 directly; only grandparent h/c touch global.
template <bool LEAF>
__global__ __launch_bounds__(256, 3) void fused_kernel(
    const int* __restrict__ x_id, const f16_t* __restrict__ P,
    const f16_t* __restrict__ UreT, const f16_t* __restrict__ Hc,
    const f16_t* __restrict__ Cc, f16_t* __restrict__ Hout,
    f16_t* __restrict__ Cout, const float* __restrict__ W_out,
    const float* __restrict__ b_out, float* __restrict__ out, int s1, int M1) {
  __shared__ __align__(16) f16_t A_sh[64 * AST];
  __shared__ __align__(16) f16_t A2_sh[32 * AST];
  __shared__ __align__(16) f16_t B_sh[128 * 40];
  __shared__ f16_t C_sh[32 * 160];
  const int tid = threadIdx.x;
  const int wid = tid >> 6, lane = tid & 63, l15 = lane & 15, q = lane >> 4;
  const int p0 = blockIdx.x * 32;
  const long childbase = 2L * s1 + 1 + 2 * p0;   // node id of first child (LEAF)

  // ---- stage A: 64 child h rows ----
#pragma unroll
  for (int i = 0; i < 5; ++i) {
    int ch = tid + 256 * i;
    int r = ch / 20, kc = (ch % 20) * 8;
    f16x8 v;
    if (LEAF) {
      int xv = x_id[childbase + r];
      v = *(const f16x8*)&Hc[(long)xv * HP + kc];      // Hc = Hleaf
    } else {
      v = *(const f16x8*)&Hc[(long)(2 * p0 + r) * HP + kc];
    }
    *(f16x8*)&A_sh[r * AST + kc] = v;
  }
  __syncthreads();

  // ---- pass 1: level s1 (32 parents) ----
  int xvp[2], xvl[2], xvr[2];
#pragma unroll
  for (int rr = 0; rr < 2; ++rr) {
    int pl = 8 * wid + 2 * q + rr;
    long pn = (long)s1 + p0 + pl;
    xvp[rr] = x_id[pn];
    if (LEAF) {
      xvl[rr] = x_id[childbase + 2 * pl];
      xvr[rr] = x_id[childbase + 2 * pl + 1];
    }
  }
  float oacc1[2][5] = {};

  for (int jt = 0; jt < 5; ++jt) {
    const int j0 = jt * 32;
    f32x4 acc[4][2];
#pragma unroll
    for (int g = 0; g < 4; ++g)
#pragma unroll
      for (int jh = 0; jh < 2; ++jh) acc[g][jh] = zero4();

    for (int kk = 0; kk < HP; kk += 32) {
#pragma unroll
      for (int i = 0; i < 2; ++i) {
        int ch = tid + 256 * i;
        int cidx = ch >> 2, kc = (ch & 3) * 8;
        int g = cidx >> 5, jj = cidx & 31;
        int col = g * HP + j0 + jj;
        *(f16x8*)&B_sh[cidx * 40 + kc] = *(const f16x8*)&UreT[col * HP + kk + kc];
      }
      __syncthreads();
      f16x8 af = *(const f16x8*)&A_sh[(16 * wid + l15) * AST + kk + q * 8];
#pragma unroll
      for (int g = 0; g < 4; ++g)
#pragma unroll
        for (int jh = 0; jh < 2; ++jh) {
          f16x8 bfr = *(const f16x8*)&B_sh[(g * 32 + jh * 16 + l15) * 40 + q * 8];
          acc[g][jh] = __builtin_amdgcn_mfma_f32_16x16x32_f16(af, bfr, acc[g][jh], 0, 0, 0);
        }
      __syncthreads();
    }

#pragma unroll
    for (int rr = 0; rr < 2; ++rr) {
      const int r = rr * 2;
      const int lr0 = 16 * wid + q * 4 + r;   // even child row
      const int pl = lr0 >> 1;                // local parent 0..31
      const f16_t* Prp = P + (long)xvp[rr] * NCOL;
#pragma unroll
      for (int jh = 0; jh < 2; ++jh) {
        const int j = j0 + jh * 16 + l15;
        f16x4 pp = *(const f16x4*)&Prp[j * 4];
        float ipre = (float)pp[0] + acc[0][jh][r] + acc[0][jh][r + 1];
        float opre = (float)pp[1] + acc[1][jh][r] + acc[1][jh][r + 1];
        float upre = (float)pp[2] + acc[2][jh][r] + acc[2][jh][r + 1];
        float pf   = (float)pp[3];
        float fl = sigf(pf + acc[3][jh][r]);
        float fr = sigf(pf + acc[3][jh][r + 1]);
        float clv, crv;
        if (LEAF) {
          clv = (float)Cc[(long)xvl[rr] * HP + j];    // Cc = Cleaf
          crv = (float)Cc[(long)xvr[rr] * HP + j];
        } else {
          clv = (float)Cc[(long)(2 * p0 + lr0) * HP + j];
          crv = (float)Cc[(long)(2 * p0 + lr0 + 1) * HP + j];
        }
        float cn = sigf(ipre) * tanhf_(upre) + fl * clv + fr * crv;
        float hn = sigf(opre) * tanhf_(cn);
        A2_sh[pl * AST + j] = (f16_t)hn;
        C_sh[pl * 160 + j] = (f16_t)cn;
        int wbase = (j < 150) ? j * 5 : 0;            // hn==0 on pads
#pragma unroll
        for (int m = 0; m < 5; ++m) oacc1[rr][m] += hn * W_out[wbase + m];
      }
    }
  }

#pragma unroll
  for (int rr = 0; rr < 2; ++rr) {
    int pl = 8 * wid + 2 * q + rr;
#pragma unroll
    for (int m = 0; m < 5; ++m) {
      float v = oacc1[rr][m];
      v += __shfl_xor(v, 1);
      v += __shfl_xor(v, 2);
      v += __shfl_xor(v, 4);
      v += __shfl_xor(v, 8);
      if (l15 == 0) out[((long)s1 + p0 + pl) * 5 + m] = v + b_out[m];
    }
  }

  // ---- pass 2: level (s1-1)/2 (16 grandparents) ----
  const int s2 = (s1 - 1) >> 1;
  const int p02 = p0 >> 1;
  const bool act2 = (wid < 2);
  int xvp2[2];
#pragma unroll
  for (int rr = 0; rr < 2; ++rr) {
    int pl = 8 * wid + 2 * q + rr;
    long pn = (long)s2 + p02 + (act2 ? pl : 0);
    xvp2[rr] = x_id[pn];
  }
  float oacc2[2][5] = {};

  for (int jt = 0; jt < 5; ++jt) {
    const int j0 = jt * 32;
    f32x4 acc[4][2];
#pragma unroll
    for (int g = 0; g < 4; ++g)
#pragma unroll
      for (int jh = 0; jh < 2; ++jh) acc[g][jh] = zero4();

    for (int kk = 0; kk < HP; kk += 32) {
#pragma unroll
      for (int i = 0; i < 2; ++i) {
        int ch = tid + 256 * i;
        int cidx = ch >> 2, kc = (ch & 3) * 8;
        int g = cidx >> 5, jj = cidx & 31;
        int col = g * HP + j0 + jj;
        *(f16x8*)&B_sh[cidx * 40 + kc] = *(const f16x8*)&UreT[col * HP + kk + kc];
      }
      __syncthreads();      // also orders pass-1 A2/C_sh writes before reads
      if (act2) {
        f16x8 af = *(const f16x8*)&A2_sh[(16 * wid + l15) * AST + kk + q * 8];
#pragma unroll
        for (int g = 0; g < 4; ++g)
#pragma unroll
          for (int jh = 0; jh < 2; ++jh) {
            f16x8 bfr = *(const f16x8*)&B_sh[(g * 32 + jh * 16 + l15) * 40 + q * 8];
            acc[g][jh] = __builtin_amdgcn_mfma_f32_16x16x32_f16(af, bfr, acc[g][jh], 0, 0, 0);
          }
      }
      __syncthreads();
    }

    if (act2) {
#pragma unroll
      for (int rr = 0; rr < 2; ++rr) {
        const int r = rr * 2;
        const int lr0 = 16 * wid + q * 4 + r;   // 0..31
        const int pl = lr0 >> 1;                // 0..15
        const f16_t* Prp = P + (long)xvp2[rr] * NCOL;
#pragma unroll
        for (int jh = 0; jh < 2; ++jh) {
          const int j = j0 + jh * 16 + l15;
          f16x4 pp = *(const f16x4*)&Prp[j * 4];
          float ipre = (float)pp[0] + acc[0][jh][r] + acc[0][jh][r + 1];
          float opre = (float)pp[1] + acc[1][jh][r] + acc[1][jh][r + 1];
          float upre = (float)pp[2] + acc[2][jh][r] + acc[2][jh][r + 1];
          float pf   = (float)pp[3];
          float fl = sigf(pf + acc[3][jh][r]);
          float fr = sigf(pf + acc[3][jh][r + 1]);
          float clv = (float)C_sh[lr0 * 160 + j];
          float crv = (float)C_sh[(lr0 + 1) * 160 + j];
          float cn = sigf(ipre) * tanhf_(upre) + fl * clv + fr * crv;
          float hn = sigf(opre) * tanhf_(cn);
          Hout[(long)(p02 + pl) * HP + j] = (f16_t)hn;
          Cout[(long)(p02 + pl) * HP + j] = (f16_t)cn;
          int wbase = (j < 150) ? j * 5 : 0;
#pragma unroll
          for (int m = 0; m < 5; ++m) oacc2[rr][m] += hn * W_out[wbase + m];
        }
      }
    }
  }

  if (act2) {
#pragma unroll
    for (int rr = 0; rr < 2; ++rr) {
      int pl = 8 * wid + 2 * q + rr;
#pragma unroll
      for (int m = 0; m < 5; ++m) {
        float v = oacc2[rr][m];
        v += __shfl_xor(v, 1);
        v += __shfl_xor(v, 2);
        v += __shfl_xor(v, 4);
        v += __shfl_xor(v, 8);
        if (l15 == 0) out[((long)s2 + p02 + pl) * 5 + m] = v + b_out[m];
      }
    }
  }
}

// ---------------- single-level tile for the tail (unchanged, proven) -------
__device__ __forceinline__ void level_tile(
    const int* __restrict__ x_id, const f16_t* __restrict__ P,
    const f16_t* __restrict__ UreT, const f16_t* __restrict__ h_child,
    const f16_t* __restrict__ c_child, f16_t* __restrict__ h_par,
    f16_t* __restrict__ c_par, const float* Wo, const float* __restrict__ b_out,
    float* __restrict__ out, int s, int M, int p0, f16_t* A_sh, f16_t* B_sh) {
  const int tid = threadIdx.x;
  const int wid = tid >> 6, lane = tid & 63, l15 = lane & 15, q = lane >> 4;
  int rowsValid = 2 * M - 2 * p0;
  if (rowsValid > 64) rowsValid = 64;

#pragma unroll
  for (int i = 0; i < 5; ++i) {
    int ch = tid + 256 * i;
    int r = ch / 20, kc = (ch % 20) * 8;
    f16x8 v;
    if (r < rowsValid) v = *(const f16x8*)&h_child[(long)(2 * p0 + r) * HP + kc];
    else v = zero8();
    *(f16x8*)&A_sh[r * 184 + kc] = v;
  }
  __syncthreads();

  int xvp[2]; long pnode[2]; int plg[2]; bool valid[2]; int lr0v[2];
#pragma unroll
  for (int rr = 0; rr < 2; ++rr) {
    int lr0 = 16 * wid + q * 4 + rr * 2;
    int pl = lr0 >> 1;
    valid[rr] = (p0 + pl) < M;
    long pn = (long)s + p0 + (valid[rr] ? pl : 0);
    pnode[rr] = pn; plg[rr] = p0 + pl; lr0v[rr] = lr0;
    xvp[rr] = x_id[pn];
  }

  float oacc[2][5];
#pragma unroll
  for (int rr = 0; rr < 2; ++rr)
#pragma unroll
    for (int m = 0; m < 5; ++m) oacc[rr][m] = 0.0f;

  for (int jt = 0; jt < 5; ++jt) {
    const int j0 = jt * 32;
    f32x4 acc[4][2];
#pragma unroll
    for (int g = 0; g < 4; ++g)
#pragma unroll
      for (int jh = 0; jh < 2; ++jh) acc[g][jh] = zero4();

    for (int kk = 0; kk < HP; kk += 32) {
#pragma unroll
      for (int i = 0; i < 2; ++i) {
        int ch = tid + 256 * i;
        int cidx = ch >> 2, kc = (ch & 3) * 8;
        int g = cidx >> 5, jj = cidx & 31;
        int col = g * HP + j0 + jj;
        *(f16x8*)&B_sh[cidx * 40 + kc] = *(const f16x8*)&UreT[col * HP + kk + kc];
      }
      __syncthreads();
      f16x8 af = *(const f16x8*)&A_sh[(16 * wid + l15) * 184 + kk + q * 8];
#pragma unroll
      for (int g = 0; g < 4; ++g)
#pragma unroll
        for (int jh = 0; jh < 2; ++jh) {
          f16x8 bfr = *(const f16x8*)&B_sh[(g * 32 + jh * 16 + l15) * 40 + q * 8];
          acc[g][jh] = __builtin_amdgcn_mfma_f32_16x16x32_f16(af, bfr, acc[g][jh], 0, 0, 0);
        }
      __syncthreads();
    }

#pragma unroll
    for (int rr = 0; rr < 2; ++rr) {
      const int r = rr * 2;
      const f16_t* Prp = P + (long)xvp[rr] * NCOL;
#pragma unroll
      for (int jh = 0; jh < 2; ++jh) {
        const int j = j0 + jh * 16 + l15;
        f16x4 pp = *(const f16x4*)&Prp[j * 4];
        float ipre = (float)pp[0] + acc[0][jh][r] + acc[0][jh][r + 1];
        float opre = (float)pp[1] + acc[1][jh][r] + acc[1][jh][r + 1];
        float upre = (float)pp[2] + acc[2][jh][r] + acc[2][jh][r + 1];
        float pf   = (float)pp[3];
        float fl = sigf(pf + acc[3][jh][r]);
        float fr = sigf(pf + acc[3][jh][r + 1]);
        float clv = valid[rr] ? (float)c_child[(long)(2 * p0 + lr0v[rr]) * HP + j] : 0.0f;
        float crv = valid[rr] ? (float)c_child[(long)(2 * p0 + lr0v[rr] + 1) * HP + j] : 0.0f;
        float cn = sigf(ipre) * tanhf_(upre) + fl * clv + fr * crv;
        float hn = sigf(opre) * tanhf_(cn);
        if (valid[rr]) {
          h_par[(long)plg[rr] * HP + j] = (f16_t)hn;
          c_par[(long)plg[rr] * HP + j] = (f16_t)cn;
        }
#pragma unroll
        for (int m = 0; m < 5; ++m) oacc[rr][m] += hn * Wo[j * 5 + m];
      }
    }
  }

#pragma unroll
  for (int rr = 0; rr < 2; ++rr) {
#pragma unroll
    for (int m = 0; m < 5; ++m) {
      float v = oacc[rr][m];
      v += __shfl_xor(v, 1);
      v += __shfl_xor(v, 2);
      v += __shfl_xor(v, 4);
      v += __shfl_xor(v, 8);
      if (l15 == 0 && valid[rr]) out[pnode[rr] * 5 + m] = v + b_out[m];
    }
  }
}

// Levels 5..0 (M<=32): one block, barriers between levels.
__global__ __launch_bounds__(256, 4) void tail_kernel(
    const int* __restrict__ x_id, const f16_t* __restrict__ P,
    const f16_t* __restrict__ UreT, f16_t* __restrict__ HA, f16_t* __restrict__ HB,
    f16_t* __restrict__ CA, f16_t* __restrict__ CB, const float* __restrict__ W_out,
    const float* __restrict__ b_out, float* __restrict__ out) {
  __shared__ __align__(16) f16_t A_sh[64 * 184];
  __shared__ __align__(16) f16_t B_sh[128 * 40];
  __shared__ float Wo[800];
  for (int i = threadIdx.x; i < 800; i += 256) Wo[i] = (i < 750) ? W_out[i] : 0.0f;
  for (int lvl = 5; lvl >= 0; --lvl) {
    int s = (1 << lvl) - 1, M = 1 << lvl;
    const f16_t* hc = ((lvl + 1) & 1) ? HA : HB;
    const f16_t* cc = ((lvl + 1) & 1) ? CA : CB;
    f16_t* hp = (lvl & 1) ? HA : HB;
    f16_t* cp = (lvl & 1) ? CA : CB;
    level_tile(x_id, P, UreT, hc, cc, hp, cp, Wo, b_out, out, s, M, 0, A_sh, B_sh);
    __syncthreads();
  }
}

extern "C" void kernel_launch(void* const* d_in, const int* in_sizes, int n_in,
                              void* d_out, int out_size, void* d_ws, size_t ws_size,
                              hipStream_t stream) {
  const int* x_id   = (const int*)d_in[0];
  const float* emb  = (const float*)d_in[1];
  const float* W_iou = (const float*)d_in[2];
  const float* U_iou = (const float*)d_in[3];
  const float* b_iou = (const float*)d_in[4];
  const float* W_f   = (const float*)d_in[5];
  const float* U_f   = (const float*)d_in[6];
  const float* b_f   = (const float*)d_in[7];
  const float* W_out = (const float*)d_in[8];
  const float* b_out = (const float*)d_in[9];
  float* out = (float*)d_out;
  char* ws = (char*)d_ws;

  // workspace carve (bytes): total 182,103,040
  f16_t* WreT  = (f16_t*)(ws + 0);              // 409,600
  f16_t* UreT  = (f16_t*)(ws + 409600);         // 204,800
  float* bre   = (float*)(ws + 614400);         // 2,560
  f16_t* P     = (f16_t*)(ws + 616960);         // 64,000,000
  f16_t* Hleaf = (f16_t*)(ws + 64616960);       // 16,000,000
  f16_t* Cleaf = (f16_t*)(ws + 80616960);       // 16,000,000
  float* Oleaf = (float*)(ws + 96616960);       // 1,600,000 (50000 x 8 f32)
  f16_t* HX    = (f16_t*)(ws + 98216960);       // 20,971,520 (65536 rows)
  f16_t* HY    = (f16_t*)(ws + 119188480);      // 20,971,520
  f16_t* CX    = (f16_t*)(ws + 140160000);      // 20,971,520
  f16_t* CY    = (f16_t*)(ws + 161131520);      // 20,971,520

  prep_params<<<1203, 256, 0, stream>>>(W_iou, U_iou, b_iou, W_f, U_f, b_f, WreT, UreT, bre);
  gemm_p<<<782, 256, 0, stream>>>(emb, WreT, bre, P);
  leafhc_kernel<<<15625, 256, 0, stream>>>(P, Hleaf, Cleaf);
  oleaf_kernel<<<3125, 256, 0, stream>>>(Hleaf, W_out, b_out, Oleaf);
  leafout_kernel<<<1024, 256, 0, stream>>>(x_id, Oleaf, out);

  // levels 17+16 -> HX/CX
  fused_kernel<true><<<4096, 256, 0, stream>>>(x_id, P, UreT, Hleaf, Cleaf, HX, CX,
                                               W_out, b_out, out, (1 << 17) - 1, 1 << 17);
  // (15,14): HX -> HY; (13,12): HY -> HX; (11,10): HX -> HY; (9,8): HY -> HX; (7,6): HX -> HY
  fused_kernel<false><<<1024, 256, 0, stream>>>(x_id, P, UreT, HX, CX, HY, CY,
                                                W_out, b_out, out, (1 << 15) - 1, 1 << 15);
  fused_kernel<false><<<256, 256, 0, stream>>>(x_id, P, UreT, HY, CY, HX, CX,
                                               W_out, b_out, out, (1 << 13) - 1, 1 << 13);
  fused_kernel<false><<<64, 256, 0, stream>>>(x_id, P, UreT, HX, CX, HY, CY,
                                              W_out, b_out, out, (1 << 11) - 1, 1 << 11);
  fused_kernel<false><<<16, 256, 0, stream>>>(x_id, P, UreT, HY, CY, HX, CX,
                                              W_out, b_out, out, (1 << 9) - 1, 1 << 9);
  fused_kernel<false><<<4, 256, 0, stream>>>(x_id, P, UreT, HX, CX, HY, CY,
                                             W_out, b_out, out, (1 << 7) - 1, 1 << 7);
  // levels 5..0 (L6 children sit in HY/CY)
  tail_kernel<<<1, 256, 0, stream>>>(x_id, P, UreT, HX, HY, CX, CY, W_out, b_out, out);

  (void)in_sizes; (void)n_in; (void)out_size; (void)ws_size;
}